// Round 14
// baseline (474.479 us; speedup 1.0000x reference)
//
#include <hip/hip_runtime.h>
#include <hip/hip_bf16.h>
#include <cstdint>

// Problem constants
#define DPROJ  8384

typedef __attribute__((ext_vector_type(8))) short short8;
typedef __attribute__((ext_vector_type(4))) short sh4;
typedef __attribute__((ext_vector_type(2))) short sh2;
typedef __attribute__((ext_vector_type(4))) float f32x4;

// workspace offsets (float units). zx is bf16 (shorts).
#define ZX16_OFF   0ul          // bf16 zx [4096][8384]
#define DTB_OFF    17170432ul   // [b][h][l] dt (softplus'd)
#define ACU_OFF    17432576ul   // [b][h][l] within-chunk cumsum of dt*A
#define CBT_OFF    17694720ul   // bf16 cbtT [b][c][l][s]
#define ST_OFF     18219008ul   // [b][c][h][p][n] states -> prev_states (fp32)
#define YB_OFF     22413312ul   // bf16 yb [b][h][l][p] ssd output
#define HALO_OFF   39190528ul   // bf16 halo
#define U16_OFF    39393280ul   // bf16 u (dead after in_proj)
#define WIN16_OFF  43587584ul   // bf16 W_in (dead after in_proj)
#define WOUT16_OFF 39393280ul   // bf16 W_out (aliases u16)

__device__ __forceinline__ short f2bf(float x) {
  union { float f; uint32_t u; } v{x};
  uint32_t r = (v.u + 0x7fff + ((v.u >> 16) & 1)) >> 16;
  return (short)r;
}
__device__ __forceinline__ float bf2f(short s) {
  union { uint32_t u; float f; } v;
  v.u = ((uint32_t)(uint16_t)s) << 16;
  return v.f;
}

// ---------------- fp32 -> bf16 cast (8 elems/thread) -------------------------
__global__ __launch_bounds__(256) void cast_bf16_kernel(
    const float* __restrict__ in, short* __restrict__ out, int n8) {
  int i = blockIdx.x * 256 + threadIdx.x;
  if (i >= n8) return;
  const float4* p = (const float4*)(in + (size_t)i * 8);
  float4 a = p[0], b = p[1];
  short8 o;
  o[0] = f2bf(a.x); o[1] = f2bf(a.y); o[2] = f2bf(a.z); o[3] = f2bf(a.w);
  o[4] = f2bf(b.x); o[5] = f2bf(b.y); o[6] = f2bf(b.z); o[7] = f2bf(b.w);
  *(short8*)(out + (size_t)i * 8) = o;
}

__device__ __forceinline__ void gload16(const void* g, const void* l) {
  __builtin_amdgcn_global_load_lds(
      (const __attribute__((address_space(1))) void*)g,
      (__attribute__((address_space(3))) void*)l, 16, 0, 0);
}

// ---- 256x256 bf16 GEMM (NT), BK=64, 8 waves (2x4): max barrier amortization -
// Same verified 2-barrier loop + XOR swizzle; 64 MFMA/K-tile/wave.
template <int OUTBF>
__global__ __launch_bounds__(512) void gemm_huge(
    const short* __restrict__ A, int lda, const short* __restrict__ B, int ldb,
    void* __restrict__ Cv, int ldc, int K, int Nvalid) {
  const int orig = blockIdx.x + gridDim.x * blockIdx.y;
  const int xcd = orig & 7;
  const int cid = orig >> 3;
  const int rpx = gridDim.y >> 3;
  const int tn = cid / rpx;
  const int tm = xcd * rpx + (cid % rpx);
  __shared__ __align__(16) short As[256 * 64];  // 32KB
  __shared__ __align__(16) short Bs[256 * 64];  // 32KB
  const int t = threadIdx.x;
  const int w = t >> 6, lane = t & 63;
  const int wm = w >> 2, wn = w & 3;
  const int m0 = tm * 256, n0 = tn * 256;
  const int fr = lane & 15;
  const int cik = lane >> 4;
  const int frs = fr & 7;
  const int rl = t >> 3;           // 0..63
  const int sch = ((t & 7) ^ (rl & 7)) << 3;
  const short* pa_[4];
  const short* pb_[4];
#pragma unroll
  for (int c = 0; c < 4; ++c) {
    pa_[c] = A + (size_t)(m0 + c * 64 + rl) * lda + sch;
    int br = n0 + c * 64 + rl;
    if (br > Nvalid - 1) br = Nvalid - 1;
    pb_[c] = B + (size_t)br * ldb + sch;
  }
  f32x4 acc[8][4];
#pragma unroll
  for (int i = 0; i < 8; ++i)
#pragma unroll
    for (int j = 0; j < 4; ++j) acc[i][j] = (f32x4){0.f, 0.f, 0.f, 0.f};

  for (int k0 = 0; k0 < K; k0 += 64) {
#pragma unroll
    for (int c = 0; c < 4; ++c) {
      gload16(pa_[c] + k0, &As[c * 4096 + w * 512 + lane * 8]);
      gload16(pb_[c] + k0, &Bs[c * 4096 + w * 512 + lane * 8]);
    }
    __syncthreads();
#pragma unroll
    for (int kk = 0; kk < 2; ++kk) {
      const int ci = kk * 4 + cik;
      short8 bg[4];
#pragma unroll
      for (int j = 0; j < 4; ++j) {
        const int rb = wn * 64 + j * 16 + fr;
        bg[j] = *(const short8*)&Bs[rb * 64 + ((ci ^ (rb & 7)) << 3)];
      }
#pragma unroll
      for (int io = 0; io < 2; ++io) {
        short8 af[4];
#pragma unroll
        for (int ii = 0; ii < 4; ++ii) {
          const int ra = wm * 128 + (io * 4 + ii) * 16 + fr;
          af[ii] = *(const short8*)&As[ra * 64 + ((ci ^ (ra & 7)) << 3)];
        }
#pragma unroll
        for (int ii = 0; ii < 4; ++ii)
#pragma unroll
          for (int j = 0; j < 4; ++j)
            acc[io * 4 + ii][j] = __builtin_amdgcn_mfma_f32_16x16x32_bf16(
                af[ii], bg[j], acc[io * 4 + ii][j], 0, 0, 0);
      }
    }
    __syncthreads();
  }
#pragma unroll
  for (int i = 0; i < 8; ++i) {
    const int row = m0 + wm * 128 + i * 16 + (lane >> 4) * 4;
#pragma unroll
    for (int j = 0; j < 4; ++j) {
      const int col = n0 + wn * 64 + j * 16 + fr;
      if (col < Nvalid) {
#pragma unroll
        for (int r = 0; r < 4; ++r) {
          if (OUTBF)
            ((short*)Cv)[(size_t)(row + r) * ldc + col] = f2bf(acc[i][j][r]);
          else
            ((float*)Cv)[(size_t)(row + r) * ldc + col] = acc[i][j][r];
        }
      }
    }
  }
}

// ---- 256x128 bf16 GEMM (NT), BK=64, 8 waves (kept for out_proj) -------------
template <int OUTBF>
__global__ __launch_bounds__(512) void gemm_big(
    const short* __restrict__ A, int lda, const short* __restrict__ B, int ldb,
    void* __restrict__ Cv, int ldc, int K, int Nvalid) {
  const int orig = blockIdx.x + gridDim.x * blockIdx.y;
  const int xcd = orig & 7;
  const int cid = orig >> 3;
  const int rpx = gridDim.y >> 3;
  const int tn = cid / rpx;
  const int tm = xcd * rpx + (cid % rpx);
  __shared__ __align__(16) short As[256 * 64];  // 32KB
  __shared__ __align__(16) short Bs[128 * 64];  // 16KB
  const int t = threadIdx.x;
  const int w = t >> 6, lane = t & 63;
  const int m0 = tm * 256, n0 = tn * 128;
  const int wr = (w >> 1) * 64, wc = (w & 1) * 64;
  const int fr = lane & 15;
  const int cik = lane >> 4;
  const int frs = fr & 7;
  const int rl = t >> 3;           // 0..63
  const int sch = ((t & 7) ^ (rl & 7)) << 3;
  const short* pa_[4];
  const short* pb_[2];
#pragma unroll
  for (int c = 0; c < 4; ++c)
    pa_[c] = A + (size_t)(m0 + c * 64 + rl) * lda + sch;
#pragma unroll
  for (int c = 0; c < 2; ++c) {
    int br = n0 + c * 64 + rl;
    if (br > Nvalid - 1) br = Nvalid - 1;
    pb_[c] = B + (size_t)br * ldb + sch;
  }
  f32x4 acc[4][4];
#pragma unroll
  for (int i = 0; i < 4; ++i)
#pragma unroll
    for (int j = 0; j < 4; ++j) acc[i][j] = (f32x4){0.f, 0.f, 0.f, 0.f};

  for (int k0 = 0; k0 < K; k0 += 64) {
#pragma unroll
    for (int c = 0; c < 4; ++c)
      gload16(pa_[c] + k0, &As[c * 4096 + w * 512 + lane * 8]);
#pragma unroll
    for (int c = 0; c < 2; ++c)
      gload16(pb_[c] + k0, &Bs[c * 4096 + w * 512 + lane * 8]);
    __syncthreads();
#pragma unroll
    for (int kk = 0; kk < 2; ++kk) {
      const int ci = kk * 4 + cik;
      short8 af[4], bg[4];
#pragma unroll
      for (int i = 0; i < 4; ++i) {
        const int ra = wr + i * 16 + fr;
        const int rb = wc + i * 16 + fr;
        af[i] = *(const short8*)&As[ra * 64 + ((ci ^ frs) << 3)];
        bg[i] = *(const short8*)&Bs[rb * 64 + ((ci ^ frs) << 3)];
      }
#pragma unroll
      for (int i = 0; i < 4; ++i)
#pragma unroll
        for (int j = 0; j < 4; ++j)
          acc[i][j] = __builtin_amdgcn_mfma_f32_16x16x32_bf16(af[i], bg[j],
                                                              acc[i][j], 0, 0, 0);
    }
    __syncthreads();
  }
#pragma unroll
  for (int i = 0; i < 4; ++i) {
    const int row = m0 + wr + i * 16 + (lane >> 4) * 4;
#pragma unroll
    for (int j = 0; j < 4; ++j) {
      const int col = n0 + wc + j * 16 + fr;
      if (col < Nvalid) {
#pragma unroll
        for (int r = 0; r < 4; ++r) {
          if (OUTBF)
            ((short*)Cv)[(size_t)(row + r) * ldc + col] = f2bf(acc[i][j][r]);
          else
            ((float*)Cv)[(size_t)(row + r) * ldc + col] = acc[i][j][r];
        }
      }
    }
  }
}

// ---------------- conv halo save (bf16, before in-place conv) ----------------
__global__ __launch_bounds__(256) void halo_kernel(const short* __restrict__ zx,
                                                   short* __restrict__ halo) {
  int idx = blockIdx.x * 256 + threadIdx.x;
  int ch = idx % 4224;
  int r = idx / 4224;
  int j = r % 3;
  int r2 = r / 3;
  int lc = r2 & 15, b = r2 >> 4;
  int l = lc * 128 - 3 + j;
  halo[idx] = (l < 0) ? (short)0 : zx[(size_t)(b * 2048 + l) * DPROJ + 4096 + ch];
}

// -------- causal conv1d(4) + silu, in place, 2 channels per thread -----------
__global__ __launch_bounds__(256) void conv_kernel(short* __restrict__ zx,
                                                   const short* __restrict__ halo,
                                                   const float* __restrict__ cw,
                                                   const float* __restrict__ cb) {
  int idx = blockIdx.x * 256 + threadIdx.x;  // < 2*16*2112
  int chp = idx % 2112;
  int r = idx / 2112;
  int ch = chp * 2;
  int lc = r & 15, b = r >> 4;
  float w0a = cw[ch * 4 + 0], w1a = cw[ch * 4 + 1], w2a = cw[ch * 4 + 2],
        w3a = cw[ch * 4 + 3];
  float w0b = cw[ch * 4 + 4], w1b = cw[ch * 4 + 5], w2b = cw[ch * 4 + 6],
        w3b = cw[ch * 4 + 7];
  float ba = cb[ch], bb = cb[ch + 1];
  const short* hp = halo + (size_t)r * 3 * 4224 + ch;
  sh2 h0 = *(const sh2*)hp;
  sh2 h1 = *(const sh2*)(hp + 4224);
  sh2 h2 = *(const sh2*)(hp + 8448);
  float xa3 = bf2f(h0[0]), xb3 = bf2f(h0[1]);
  float xa2 = bf2f(h1[0]), xb2 = bf2f(h1[1]);
  float xa1 = bf2f(h2[0]), xb1 = bf2f(h2[1]);
  size_t base = (size_t)(b * 2048 + lc * 128) * DPROJ + 4096 + ch;
  for (int i = 0; i < 128; ++i) {
    sh2 xv = *(const sh2*)&zx[base];
    float xa0 = bf2f(xv[0]), xb0 = bf2f(xv[1]);
    float va = ba + w0a * xa3 + w1a * xa2 + w2a * xa1 + w3a * xa0;
    float vb = bb + w0b * xb3 + w1b * xb2 + w2b * xb1 + w3b * xb0;
    va = va / (1.f + __expf(-va));
    vb = vb / (1.f + __expf(-vb));
    sh2 o;
    o[0] = f2bf(va);
    o[1] = f2bf(vb);
    *(sh2*)&zx[base] = o;
    xa3 = xa2; xa2 = xa1; xa1 = xa0;
    xb3 = xb2; xb2 = xb1; xb1 = xb0;
    base += DPROJ;
  }
}

// ---------------- dt softplus + per-chunk cumsum of dt*A ---------------------
__global__ __launch_bounds__(256) void dtacum_kernel(
    const short* __restrict__ zx, const float* __restrict__ dt_bias,
    const float* __restrict__ A_log, float* __restrict__ dtb,
    float* __restrict__ acu) {
  int bid = blockIdx.x;
  int c = bid & 7, h = (bid >> 3) & 63, b = bid >> 9;
  int s = threadIdx.x;
  int tok = b * 2048 + c * 256 + s;
  float raw = bf2f(zx[(size_t)tok * DPROJ + 8320 + h]) + dt_bias[h];
  float dtv = (raw > 20.f) ? raw : log1pf(expf(raw));
  float A = -expf(A_log[h]);
  __shared__ float sc[256];
  sc[s] = dtv * A;
  __syncthreads();
  for (int off = 1; off < 256; off <<= 1) {
    float v = (s >= off) ? sc[s - off] : 0.f;
    __syncthreads();
    sc[s] += v;
    __syncthreads();
  }
  int o = (b * 64 + h) * 2048 + c * 256 + s;
  dtb[o] = dtv;
  acu[o] = sc[s];
}

// ---------------- CB^T per (b,c), TRANSPOSED bf16: cbtT[l][s] ----------------
__global__ __launch_bounds__(256) void cbt_kernel(const short* __restrict__ zx,
                                                  short* __restrict__ cbtT) {
  __shared__ float cl[256][33];
  __shared__ float blds[16][32];
  int bid = blockIdx.x;
  int sb = bid & 15, c = (bid >> 4) & 7, b = bid >> 7;
  int t = threadIdx.x;  // = l
  int tok0 = b * 2048 + c * 256;
  float acc[16];
#pragma unroll
  for (int i = 0; i < 16; ++i) acc[i] = 0.f;
  for (int nh = 0; nh < 2; ++nh) {
    __syncthreads();
    for (int it = 0; it < 32; ++it) {
      int e = it * 256 + t;
      int row = e >> 5, n = e & 31;
      cl[row][n] = bf2f(zx[(size_t)(tok0 + row) * DPROJ + 8256 + nh * 32 + n]);
    }
    for (int it = 0; it < 2; ++it) {
      int e = it * 256 + t;
      int row = e >> 5, n = e & 31;
      blds[row][n] =
          bf2f(zx[(size_t)(tok0 + sb * 16 + row) * DPROJ + 8192 + nh * 32 + n]);
    }
    __syncthreads();
    for (int n = 0; n < 32; ++n) {
      float cv = cl[t][n];
#pragma unroll
      for (int s2 = 0; s2 < 16; ++s2) acc[s2] += cv * blds[s2][n];
    }
  }
  short* outp = cbtT + ((size_t)(b * 8 + c) * 256 + t) * 256 + sb * 16;
#pragma unroll
  for (int s2 = 0; s2 < 16; ++s2) outp[s2] = f2bf(acc[s2]);
}

// ---------------- states (MFMA): st[p][n] = sum_s x[s,p] B[s,n] w[s] ---------
__global__ __launch_bounds__(256) void states_mfma(
    const short* __restrict__ zx, const float* __restrict__ dtb,
    const float* __restrict__ acu, float* __restrict__ st) {
  __shared__ __align__(16) short As2[64][136];  // X^T [p][k]
  __shared__ __align__(16) short Bs2[64][136];  // (B·w)^T [n][k]
  __shared__ float wl[256];
  int bid = blockIdx.x;  // (b*8+c)*64 + h
  int h = bid & 63, c = (bid >> 6) & 7, b = bid >> 9;
  int t = threadIdx.x;
  int w = t >> 6, lane = t & 63;
  int tok0 = b * 2048 + c * 256;
  int bh = (b * 64 + h) * 2048 + c * 256;
  {
    float aend = acu[bh + 255];
    wl[t] = __expf(aend - acu[bh + t]) * dtb[bh + t];
  }
  __syncthreads();
  const short* xbase = zx + (size_t)tok0 * DPROJ + 4096 + h * 64;
  const short* bbase = zx + (size_t)tok0 * DPROJ + 8192;
  const int fr = lane & 15, fko = (lane >> 4) * 8;
  const int wi = (w >> 1) * 32, wj = (w & 1) * 32;
  f32x4 acc[2][2];
#pragma unroll
  for (int i = 0; i < 2; ++i)
#pragma unroll
    for (int j = 0; j < 2; ++j) acc[i][j] = (f32x4){0.f, 0.f, 0.f, 0.f};

  for (int ph = 0; ph < 2; ++ph) {
    const int kb = ph * 128;
    if (ph) __syncthreads();
    for (int it = 0; it < 8; ++it) {
      int idx = it * 256 + t;
      int p = idx & 63, kg = idx >> 6;  // kg 0..31
      int k = kb + kg * 4;
      const short* xp = xbase + (size_t)k * DPROJ + p;
      const short* bp = bbase + (size_t)k * DPROJ + p;
      sh4 oa, ob;
#pragma unroll
      for (int r = 0; r < 4; ++r) {
        oa[r] = xp[(size_t)r * DPROJ];
        ob[r] = f2bf(bf2f(bp[(size_t)r * DPROJ]) * wl[k + r]);
      }
      *(sh4*)&As2[p][kg * 4] = oa;
      *(sh4*)&Bs2[p][kg * 4] = ob;
    }
    __syncthreads();
#pragma unroll
    for (int kk0 = 0; kk0 < 128; kk0 += 32) {
      short8 af[2], bg[2];
#pragma unroll
      for (int i = 0; i < 2; ++i) {
        af[i] = *(const short8*)&As2[wi + i * 16 + fr][kk0 + fko];
        bg[i] = *(const short8*)&Bs2[wj + i * 16 + fr][kk0 + fko];
      }
#pragma unroll
      for (int i = 0; i < 2; ++i)
#pragma unroll
        for (int j = 0; j < 2; ++j)
          acc[i][j] = __builtin_amdgcn_mfma_f32_16x16x32_bf16(af[i], bg[j],
                                                              acc[i][j], 0, 0, 0);
    }
  }
  float* out = st + ((size_t)(b * 8 + c) * 64 + h) * 4096;
  const int rq = (lane >> 4) * 4;
#pragma unroll
  for (int i = 0; i < 2; ++i) {
    int p0 = wi + i * 16 + rq;
#pragma unroll
    for (int j = 0; j < 2; ++j) {
      int n = wj + j * 16 + fr;
#pragma unroll
      for (int r = 0; r < 4; ++r)
        out[(size_t)(p0 + r) * 64 + n] = acc[i][j][r];
    }
  }
}

// ---------------- inter-chunk scan (in place states -> prev_states) ---------
__global__ __launch_bounds__(256) void chunkscan_kernel(
    const float* __restrict__ acu, float* __restrict__ st) {
  int bid = blockIdx.x;
  int pc = bid & 15, h = (bid >> 4) & 63, b = bid >> 10;
  int pn = pc * 256 + threadIdx.x;
  int abase = (b * 64 + h) * 2048;
  float run = 0.f;
  for (int c = 0; c < 8; ++c) {
    size_t idx = ((size_t)(b * 8 + c) * 64 + h) * 4096 + pn;
    float s = st[idx];
    st[idx] = run;
    float ach = acu[abase + c * 256 + 255];
    run = run * __expf(ach) + s;
  }
}

// ---------------- Y (MFMA): M=256 l, N=64 p, K=320 (256 s + 64 n) ------------
__global__ __launch_bounds__(256) void ydiag_mfma(
    const short* __restrict__ zx, const float* __restrict__ dtb,
    const float* __restrict__ acu, const short* __restrict__ cbtT,
    const float* __restrict__ st, const float* __restrict__ Dp,
    short* __restrict__ yb) {
  __shared__ __align__(16) short Xs[64][328];  // [p][k]: k<256 x, k>=256 prev
  __shared__ float acs[256];
  __shared__ float dts[256];
  int bid = blockIdx.x;  // (b*8+c)*64 + h
  int h = bid & 63, c = (bid >> 6) & 7, b = bid >> 9;
  int t = threadIdx.x;
  int w = t >> 6, lane = t & 63;
  int tok0 = b * 2048 + c * 256;
  int bh = (b * 64 + h) * 2048 + c * 256;
  acs[t] = acu[bh + t];
  dts[t] = dtb[bh + t];
  const short* xbase = zx + (size_t)tok0 * DPROJ + 4096 + h * 64;
  const float* st_b = st + ((size_t)(b * 8 + c) * 64 + h) * 4096;
  for (int it = 0; it < 16; ++it) {
    int idx = it * 256 + t;
    int p = idx & 63, kg = idx >> 6;  // kg 0..63
    const short* xp = xbase + (size_t)(kg * 4) * DPROJ + p;
    sh4 o;
    o[0] = xp[0];
    o[1] = xp[DPROJ];
    o[2] = xp[2 * DPROJ];
    o[3] = xp[3 * DPROJ];
    *(sh4*)&Xs[p][kg * 4] = o;
  }
  for (int it = 0; it < 4; ++it) {
    int idx = it * 256 + t;
    int ng = idx & 15, p = idx >> 4;
    float4 v = *(const float4*)&st_b[p * 64 + ng * 4];
    sh4 o;
    o[0] = f2bf(v.x); o[1] = f2bf(v.y); o[2] = f2bf(v.z); o[3] = f2bf(v.w);
    *(sh4*)&Xs[p][256 + ng * 4] = o;
  }
  __syncthreads();

  const int fr = lane & 15, fko = (lane >> 4) * 8;
  float Al[4], eAl[4];
#pragma unroll
  for (int i = 0; i < 4; ++i) {
    Al[i] = acs[(i * 4 + w) * 16 + fr];
    eAl[i] = __expf(Al[i]);
  }
  f32x4 acc[4][4];
#pragma unroll
  for (int i = 0; i < 4; ++i)
#pragma unroll
    for (int j = 0; j < 4; ++j) acc[i][j] = (f32x4){0.f, 0.f, 0.f, 0.f};

  const short* cbt_b = cbtT + (size_t)(b * 8 + c) * 65536;

  // masked decay part: wave w's max row-block is 12+w
  const int k0max = (12 + w) * 16 + 16;
  for (int k0 = 0; k0 < k0max; k0 += 32) {
    short8 bg[4];
#pragma unroll
    for (int j = 0; j < 4; ++j)
      bg[j] = *(const short8*)&Xs[j * 16 + fr][k0 + fko];
    const int bi = (k0 + 32 < 256) ? (k0 + 32) : 255;
    const float base = acs[bi];
    float vd[8];
#pragma unroll
    for (int jj = 0; jj < 8; ++jj) {
      int s = k0 + fko + jj;
      vd[jj] = __expf(base - acs[s]) * dts[s];
    }
#pragma unroll
    for (int i = 0; i < 4; ++i) {
      const int li0 = (i * 4 + w) * 16;
      if (k0 > li0 + 15) continue;  // fragment fully above diagonal: zero
      const int l = li0 + fr;
      const short8 cb = *(const short8*)&cbt_b[(size_t)l * 256 + k0 + fko];
      short8 af;
      if (k0 + 32 <= li0) {
        const float u = __expf(Al[i] - base);
#pragma unroll
        for (int jj = 0; jj < 8; ++jj)
          af[jj] = f2bf(bf2f(cb[jj]) * (vd[jj] * u));
      } else {
#pragma unroll
        for (int jj = 0; jj < 8; ++jj) {
          int s = k0 + fko + jj;
          float wv = 0.f;
          if (s <= l) wv = bf2f(cb[jj]) * __expf(Al[i] - acs[s]) * dts[s];
          af[jj] = f2bf(wv);
        }
      }
#pragma unroll
      for (int j = 0; j < 4; ++j)
        acc[i][j] = __builtin_amdgcn_mfma_f32_16x16x32_bf16(af, bg[j],
                                                            acc[i][j], 0, 0, 0);
    }
  }
  // Y_off part: k in [256, 320) -> n = k-256; C read straight from zx (bf16)
#pragma unroll
  for (int k0 = 256; k0 < 320; k0 += 32) {
    short8 bg[4];
#pragma unroll
    for (int j = 0; j < 4; ++j)
      bg[j] = *(const short8*)&Xs[j * 16 + fr][k0 + fko];
#pragma unroll
    for (int i = 0; i < 4; ++i) {
      const int l = (i * 4 + w) * 16 + fr;
      const short8 cv = *(const short8*)(zx + (size_t)(tok0 + l) * DPROJ +
                                         8256 + (k0 - 256) + fko);
      short8 af;
#pragma unroll
      for (int jj = 0; jj < 8; ++jj) af[jj] = f2bf(bf2f(cv[jj]) * eAl[i]);
#pragma unroll
      for (int j = 0; j < 4; ++j)
        acc[i][j] = __builtin_amdgcn_mfma_f32_16x16x32_bf16(af, bg[j],
                                                            acc[i][j], 0, 0, 0);
    }
  }
  // epilogue: + D*x, store bf16
  float Dh = Dp[h];
  const int rq = (lane >> 4) * 4;
#pragma unroll
  for (int i = 0; i < 4; ++i) {
    int l0 = (i * 4 + w) * 16 + rq;
#pragma unroll
    for (int j = 0; j < 4; ++j) {
      int p = j * 16 + fr;
      sh4 x4 = *(const sh4*)&Xs[p][l0];
      f32x4 a = acc[i][j];
#pragma unroll
      for (int r = 0; r < 4; ++r)
        yb[(size_t)(bh + l0 + r) * 64 + p] = f2bf(a[r] + Dh * bf2f(x4[r]));
    }
  }
}

// -------- gate + RMSNorm -> bf16 in place, 16 contiguous ch per thread -------
__global__ __launch_bounds__(256) void gatenorm_kernel(
    short* zx, const float* __restrict__ nw, const short* __restrict__ yb) {
  int tok = blockIdx.x;
  int b = tok >> 11, l = tok & 2047;
  int t = threadIdx.x;
  const int d0 = t * 16;                    // 16 contiguous channels
  const int h = d0 >> 6, p0 = d0 & 63;      // one h, p0..p0+15
  short8 yv8[2], zv8[2];
  yv8[0] = *(const short8*)&yb[((size_t)(b * 64 + h) * 2048 + l) * 64 + p0];
  yv8[1] = *(const short8*)&yb[((size_t)(b * 64 + h) * 2048 + l) * 64 + p0 + 8];
  zv8[0] = *(const short8*)&zx[(size_t)tok * DPROJ + d0];
  zv8[1] = *(const short8*)&zx[(size_t)tok * DPROJ + d0 + 8];
  float g[16];
  float ss = 0.f;
#pragma unroll
  for (int i = 0; i < 16; ++i) {
    float yv = bf2f(yv8[i >> 3][i & 7]);
    float zv = bf2f(zv8[i >> 3][i & 7]);
    float gv = yv * (zv / (1.f + __expf(-zv)));
    g[i] = gv;
    ss += gv * gv;
  }
  for (int off = 32; off > 0; off >>= 1) ss += __shfl_down(ss, off);
  __shared__ float red[4];
  int wid = t >> 6, lane = t & 63;
  if (lane == 0) red[wid] = ss;
  __syncthreads();
  float tot = red[0] + red[1] + red[2] + red[3];
  float scale = rsqrtf(tot * (1.f / 4096.f) + 1e-5f);
  short8 o[2];
#pragma unroll
  for (int i = 0; i < 16; ++i)
    o[i >> 3][i & 7] = f2bf(g[i] * scale * nw[d0 + i]);
  *(short8*)&zx[(size_t)tok * DPROJ + d0] = o[0];
  *(short8*)&zx[(size_t)tok * DPROJ + d0 + 8] = o[1];
}

extern "C" void kernel_launch(void* const* d_in, const int* in_sizes, int n_in,
                              void* d_out, int out_size, void* d_ws,
                              size_t ws_size, hipStream_t stream) {
  const float* u = (const float*)d_in[0];
  const float* W_in = (const float*)d_in[1];
  const float* conv_w = (const float*)d_in[2];
  const float* conv_b = (const float*)d_in[3];
  const float* dt_bias = (const float*)d_in[4];
  const float* A_log = (const float*)d_in[5];
  const float* Dp = (const float*)d_in[6];
  const float* norm_w = (const float*)d_in[7];
  const float* W_out = (const float*)d_in[8];
  float* out = (float*)d_out;
  float* ws = (float*)d_ws;

  short* zx16 = (short*)(ws + ZX16_OFF);
  float* dtb = ws + DTB_OFF;
  float* acu = ws + ACU_OFF;
  short* cbtT = (short*)(ws + CBT_OFF);
  float* st = ws + ST_OFF;
  short* yb = (short*)(ws + YB_OFF);
  short* halo = (short*)(ws + HALO_OFF);
  short* u16 = (short*)(ws + U16_OFF);
  short* win16 = (short*)(ws + WIN16_OFF);
  short* wout16 = (short*)(ws + WOUT16_OFF);

  // 0. casts for in_proj
  cast_bf16_kernel<<<4096, 256, 0, stream>>>(u, u16, 1048576);
  cast_bf16_kernel<<<8384, 256, 0, stream>>>(W_in, win16, 2146304);
  // 1. in_proj (bf16 out, 256x256 tile, BK=64): zx16 = u @ W_in^T
  gemm_huge<1><<<dim3(33, 16), 512, 0, stream>>>(u16, 2048, win16, 2048, zx16,
                                                 DPROJ, 2048, DPROJ);
  // 2. conv halo (bf16), in-place conv+silu (2 ch/thread)
  halo_kernel<<<1584, 256, 0, stream>>>(zx16, halo);
  conv_kernel<<<264, 256, 0, stream>>>(zx16, halo, conv_w, conv_b);
  // 3. dt softplus + per-chunk cumsum
  dtacum_kernel<<<1024, 256, 0, stream>>>(zx16, dt_bias, A_log, dtb, acu);
  // 4. shared C·B^T (transposed bf16)
  cbt_kernel<<<256, 256, 0, stream>>>(zx16, cbtT);
  // 5. chunk states (MFMA) + inter-chunk scan
  states_mfma<<<1024, 256, 0, stream>>>(zx16, dtb, acu, st);
  chunkscan_kernel<<<2048, 256, 0, stream>>>(acu, st);
  // 6. Y (MFMA, load-balanced) -> bf16 yb
  ydiag_mfma<<<1024, 256, 0, stream>>>(zx16, dtb, acu, cbtT, st, Dp, yb);
  // 7. W_out cast (u16 region dead now)
  cast_bf16_kernel<<<4096, 256, 0, stream>>>(W_out, wout16, 1048576);
  // 8. gate + RMSNorm -> bf16 in place over z-slice (short8)
  gatenorm_kernel<<<4096, 256, 0, stream>>>(zx16, norm_w, yb);
  // 9. out_proj (fp32 out, 256x128 tile, BK=64): out = norm(y) @ W_out^T
  gemm_big<0><<<dim3(16, 16), 512, 0, stream>>>(zx16, DPROJ, wout16, 4096, out,
                                                2048, 4096, 2048);
}

// Round 15
// 432.195 us; speedup vs baseline: 1.0978x; 1.0978x over previous
//
#include <hip/hip_runtime.h>
#include <hip/hip_bf16.h>
#include <cstdint>

// Problem constants
#define DPROJ  8384

typedef __attribute__((ext_vector_type(8))) short short8;
typedef __attribute__((ext_vector_type(4))) short sh4;
typedef __attribute__((ext_vector_type(2))) short sh2;
typedef __attribute__((ext_vector_type(4))) float f32x4;

// workspace offsets (float units). zx is bf16 (shorts).
#define ZX16_OFF   0ul          // bf16 zx [4096][8384]
#define DTB_OFF    17170432ul   // [b][h][l] dt (softplus'd)
#define ACU_OFF    17432576ul   // [b][h][l] within-chunk cumsum of dt*A
#define CBT_OFF    17694720ul   // bf16 cbtT [b][c][l][s]
#define ST_OFF     18219008ul   // [b][c][h][p][n] states -> prev_states (fp32)
#define YB_OFF     22413312ul   // bf16 yb [b][h][l][p] ssd output
#define HALO_OFF   39190528ul   // bf16 halo
#define U16_OFF    39393280ul   // bf16 u (dead after in_proj)
#define WIN16_OFF  43587584ul   // bf16 W_in (dead after in_proj)
#define WOUT16_OFF 39393280ul   // bf16 W_out (aliases u16)

__device__ __forceinline__ short f2bf(float x) {
  union { float f; uint32_t u; } v{x};
  uint32_t r = (v.u + 0x7fff + ((v.u >> 16) & 1)) >> 16;
  return (short)r;
}
__device__ __forceinline__ float bf2f(short s) {
  union { uint32_t u; float f; } v;
  v.u = ((uint32_t)(uint16_t)s) << 16;
  return v.f;
}

// ---------------- fp32 -> bf16 cast (8 elems/thread) -------------------------
__global__ __launch_bounds__(256) void cast_bf16_kernel(
    const float* __restrict__ in, short* __restrict__ out, int n8) {
  int i = blockIdx.x * 256 + threadIdx.x;
  if (i >= n8) return;
  const float4* p = (const float4*)(in + (size_t)i * 8);
  float4 a = p[0], b = p[1];
  short8 o;
  o[0] = f2bf(a.x); o[1] = f2bf(a.y); o[2] = f2bf(a.z); o[3] = f2bf(a.w);
  o[4] = f2bf(b.x); o[5] = f2bf(b.y); o[6] = f2bf(b.z); o[7] = f2bf(b.w);
  *(short8*)(out + (size_t)i * 8) = o;
}

// ---- merged cast: u (n8a) then W_in (n8b) in one dispatch -------------------
__global__ __launch_bounds__(256) void cast2_bf16_kernel(
    const float* __restrict__ ina, short* __restrict__ outa, int n8a,
    const float* __restrict__ inb, short* __restrict__ outb, int n8b) {
  int i = blockIdx.x * 256 + threadIdx.x;
  const float* in;
  short* out;
  if (i < n8a) {
    in = ina; out = outa;
  } else {
    i -= n8a;
    if (i >= n8b) return;
    in = inb; out = outb;
  }
  const float4* p = (const float4*)(in + (size_t)i * 8);
  float4 a = p[0], b = p[1];
  short8 o;
  o[0] = f2bf(a.x); o[1] = f2bf(a.y); o[2] = f2bf(a.z); o[3] = f2bf(a.w);
  o[4] = f2bf(b.x); o[5] = f2bf(b.y); o[6] = f2bf(b.z); o[7] = f2bf(b.w);
  *(short8*)(out + (size_t)i * 8) = o;
}

__device__ __forceinline__ void gload16(const void* g, const void* l) {
  __builtin_amdgcn_global_load_lds(
      (const __attribute__((address_space(1))) void*)g,
      (__attribute__((address_space(3))) void*)l, 16, 0, 0);
}

// ---- 256x128 bf16 GEMM (NT), BK=64, 8 waves (best measured: in_proj) --------
template <int OUTBF>
__global__ __launch_bounds__(512) void gemm_big(
    const short* __restrict__ A, int lda, const short* __restrict__ B, int ldb,
    void* __restrict__ Cv, int ldc, int K, int Nvalid) {
  const int orig = blockIdx.x + gridDim.x * blockIdx.y;
  const int xcd = orig & 7;
  const int cid = orig >> 3;
  const int rpx = gridDim.y >> 3;
  const int tn = cid / rpx;
  const int tm = xcd * rpx + (cid % rpx);
  __shared__ __align__(16) short As[256 * 64];  // 32KB
  __shared__ __align__(16) short Bs[128 * 64];  // 16KB
  const int t = threadIdx.x;
  const int w = t >> 6, lane = t & 63;
  const int m0 = tm * 256, n0 = tn * 128;
  const int wr = (w >> 1) * 64, wc = (w & 1) * 64;
  const int fr = lane & 15;
  const int cik = lane >> 4;
  const int frs = fr & 7;
  const int rl = t >> 3;           // 0..63
  const int sch = ((t & 7) ^ (rl & 7)) << 3;
  const short* pa_[4];
  const short* pb_[2];
#pragma unroll
  for (int c = 0; c < 4; ++c)
    pa_[c] = A + (size_t)(m0 + c * 64 + rl) * lda + sch;
#pragma unroll
  for (int c = 0; c < 2; ++c) {
    int br = n0 + c * 64 + rl;
    if (br > Nvalid - 1) br = Nvalid - 1;
    pb_[c] = B + (size_t)br * ldb + sch;
  }
  f32x4 acc[4][4];
#pragma unroll
  for (int i = 0; i < 4; ++i)
#pragma unroll
    for (int j = 0; j < 4; ++j) acc[i][j] = (f32x4){0.f, 0.f, 0.f, 0.f};

  for (int k0 = 0; k0 < K; k0 += 64) {
#pragma unroll
    for (int c = 0; c < 4; ++c)
      gload16(pa_[c] + k0, &As[c * 4096 + w * 512 + lane * 8]);
#pragma unroll
    for (int c = 0; c < 2; ++c)
      gload16(pb_[c] + k0, &Bs[c * 4096 + w * 512 + lane * 8]);
    __syncthreads();
#pragma unroll
    for (int kk = 0; kk < 2; ++kk) {
      const int ci = kk * 4 + cik;
      short8 af[4], bg[4];
#pragma unroll
      for (int i = 0; i < 4; ++i) {
        const int ra = wr + i * 16 + fr;
        const int rb = wc + i * 16 + fr;
        af[i] = *(const short8*)&As[ra * 64 + ((ci ^ frs) << 3)];
        bg[i] = *(const short8*)&Bs[rb * 64 + ((ci ^ frs) << 3)];
      }
#pragma unroll
      for (int i = 0; i < 4; ++i)
#pragma unroll
        for (int j = 0; j < 4; ++j)
          acc[i][j] = __builtin_amdgcn_mfma_f32_16x16x32_bf16(af[i], bg[j],
                                                              acc[i][j], 0, 0, 0);
    }
    __syncthreads();
  }
#pragma unroll
  for (int i = 0; i < 4; ++i) {
    const int row = m0 + wr + i * 16 + (lane >> 4) * 4;
#pragma unroll
    for (int j = 0; j < 4; ++j) {
      const int col = n0 + wc + j * 16 + fr;
      if (col < Nvalid) {
#pragma unroll
        for (int r = 0; r < 4; ++r) {
          if (OUTBF)
            ((short*)Cv)[(size_t)(row + r) * ldc + col] = f2bf(acc[i][j][r]);
          else
            ((float*)Cv)[(size_t)(row + r) * ldc + col] = acc[i][j][r];
        }
      }
    }
  }
}

// ---- 128x128 bf16 GEMM (NT), BK=64 (best measured: out_proj) ----------------
template <int OUTBF>
__global__ __launch_bounds__(256) void gemm_bf16(
    const short* __restrict__ A, int lda, const short* __restrict__ B, int ldb,
    void* __restrict__ Cv, int ldc, int K, int Nvalid) {
  const int orig = blockIdx.x + gridDim.x * blockIdx.y;
  const int xcd = orig & 7;
  const int cid = orig >> 3;
  const int rpx = gridDim.y >> 3;
  const int tn = cid / rpx;
  const int tm = xcd * rpx + (cid % rpx);
  __shared__ __align__(16) short As[128 * 64];
  __shared__ __align__(16) short Bs[128 * 64];
  const int t = threadIdx.x;
  const int w = t >> 6, lane = t & 63;
  const int m0 = tm * 128, n0 = tn * 128;
  const int wr = (w >> 1) * 64, wc = (w & 1) * 64;
  const int fr = lane & 15;
  const int cik = lane >> 4;
  const int frs = fr & 7;
  const int rl = lane >> 3;
  const int sch = ((lane & 7) ^ rl) << 3;
  const short* pa_[4];
  const short* pb_[4];
#pragma unroll
  for (int c = 0; c < 4; ++c) {
    int r = c * 32 + w * 8 + rl;
    pa_[c] = A + (size_t)(m0 + r) * lda + sch;
    int br = n0 + r;
    if (br > Nvalid - 1) br = Nvalid - 1;
    pb_[c] = B + (size_t)br * ldb + sch;
  }
  f32x4 acc[4][4];
#pragma unroll
  for (int i = 0; i < 4; ++i)
#pragma unroll
    for (int j = 0; j < 4; ++j) acc[i][j] = (f32x4){0.f, 0.f, 0.f, 0.f};

  for (int k0 = 0; k0 < K; k0 += 64) {
#pragma unroll
    for (int c = 0; c < 4; ++c) {
      gload16(pa_[c] + k0, &As[c * 2048 + w * 512 + lane * 8]);
      gload16(pb_[c] + k0, &Bs[c * 2048 + w * 512 + lane * 8]);
    }
    __syncthreads();
#pragma unroll
    for (int kk = 0; kk < 2; ++kk) {
      const int ci = kk * 4 + cik;
      short8 af[4], bg[4];
#pragma unroll
      for (int i = 0; i < 4; ++i) {
        const int ra = wr + i * 16 + fr;
        const int rb = wc + i * 16 + fr;
        af[i] = *(const short8*)&As[ra * 64 + ((ci ^ frs) << 3)];
        bg[i] = *(const short8*)&Bs[rb * 64 + ((ci ^ frs) << 3)];
      }
#pragma unroll
      for (int i = 0; i < 4; ++i)
#pragma unroll
        for (int j = 0; j < 4; ++j)
          acc[i][j] = __builtin_amdgcn_mfma_f32_16x16x32_bf16(af[i], bg[j],
                                                              acc[i][j], 0, 0, 0);
    }
    __syncthreads();
  }
#pragma unroll
  for (int i = 0; i < 4; ++i) {
    const int row = m0 + wr + i * 16 + (lane >> 4) * 4;
#pragma unroll
    for (int j = 0; j < 4; ++j) {
      const int col = n0 + wc + j * 16 + fr;
      if (col < Nvalid) {
#pragma unroll
        for (int r = 0; r < 4; ++r) {
          if (OUTBF)
            ((short*)Cv)[(size_t)(row + r) * ldc + col] = f2bf(acc[i][j][r]);
          else
            ((float*)Cv)[(size_t)(row + r) * ldc + col] = acc[i][j][r];
        }
      }
    }
  }
}

// ---------------- conv halo save (bf16, before in-place conv) ----------------
__global__ __launch_bounds__(256) void halo_kernel(const short* __restrict__ zx,
                                                   short* __restrict__ halo) {
  int idx = blockIdx.x * 256 + threadIdx.x;
  int ch = idx % 4224;
  int r = idx / 4224;
  int j = r % 3;
  int r2 = r / 3;
  int lc = r2 & 15, b = r2 >> 4;
  int l = lc * 128 - 3 + j;
  halo[idx] = (l < 0) ? (short)0 : zx[(size_t)(b * 2048 + l) * DPROJ + 4096 + ch];
}

// -------- causal conv1d(4) + silu, in place, 2 channels per thread -----------
__global__ __launch_bounds__(256) void conv_kernel(short* __restrict__ zx,
                                                   const short* __restrict__ halo,
                                                   const float* __restrict__ cw,
                                                   const float* __restrict__ cb) {
  int idx = blockIdx.x * 256 + threadIdx.x;  // < 2*16*2112
  int chp = idx % 2112;
  int r = idx / 2112;
  int ch = chp * 2;
  int lc = r & 15, b = r >> 4;
  float w0a = cw[ch * 4 + 0], w1a = cw[ch * 4 + 1], w2a = cw[ch * 4 + 2],
        w3a = cw[ch * 4 + 3];
  float w0b = cw[ch * 4 + 4], w1b = cw[ch * 4 + 5], w2b = cw[ch * 4 + 6],
        w3b = cw[ch * 4 + 7];
  float ba = cb[ch], bb = cb[ch + 1];
  const short* hp = halo + (size_t)r * 3 * 4224 + ch;
  sh2 h0 = *(const sh2*)hp;
  sh2 h1 = *(const sh2*)(hp + 4224);
  sh2 h2 = *(const sh2*)(hp + 8448);
  float xa3 = bf2f(h0[0]), xb3 = bf2f(h0[1]);
  float xa2 = bf2f(h1[0]), xb2 = bf2f(h1[1]);
  float xa1 = bf2f(h2[0]), xb1 = bf2f(h2[1]);
  size_t base = (size_t)(b * 2048 + lc * 128) * DPROJ + 4096 + ch;
  for (int i = 0; i < 128; ++i) {
    sh2 xv = *(const sh2*)&zx[base];
    float xa0 = bf2f(xv[0]), xb0 = bf2f(xv[1]);
    float va = ba + w0a * xa3 + w1a * xa2 + w2a * xa1 + w3a * xa0;
    float vb = bb + w0b * xb3 + w1b * xb2 + w2b * xb1 + w3b * xb0;
    va = va / (1.f + __expf(-va));
    vb = vb / (1.f + __expf(-vb));
    sh2 o;
    o[0] = f2bf(va);
    o[1] = f2bf(vb);
    *(sh2*)&zx[base] = o;
    xa3 = xa2; xa2 = xa1; xa1 = xa0;
    xb3 = xb2; xb2 = xb1; xb1 = xb0;
    base += DPROJ;
  }
}

// ---------------- dt softplus + per-chunk cumsum of dt*A ---------------------
__global__ __launch_bounds__(256) void dtacum_kernel(
    const short* __restrict__ zx, const float* __restrict__ dt_bias,
    const float* __restrict__ A_log, float* __restrict__ dtb,
    float* __restrict__ acu) {
  int bid = blockIdx.x;
  int c = bid & 7, h = (bid >> 3) & 63, b = bid >> 9;
  int s = threadIdx.x;
  int tok = b * 2048 + c * 256 + s;
  float raw = bf2f(zx[(size_t)tok * DPROJ + 8320 + h]) + dt_bias[h];
  float dtv = (raw > 20.f) ? raw : log1pf(expf(raw));
  float A = -expf(A_log[h]);
  __shared__ float sc[256];
  sc[s] = dtv * A;
  __syncthreads();
  for (int off = 1; off < 256; off <<= 1) {
    float v = (s >= off) ? sc[s - off] : 0.f;
    __syncthreads();
    sc[s] += v;
    __syncthreads();
  }
  int o = (b * 64 + h) * 2048 + c * 256 + s;
  dtb[o] = dtv;
  acu[o] = sc[s];
}

// ---------------- CB^T per (b,c), TRANSPOSED bf16: cbtT[l][s] ----------------
__global__ __launch_bounds__(256) void cbt_kernel(const short* __restrict__ zx,
                                                  short* __restrict__ cbtT) {
  __shared__ float cl[256][33];
  __shared__ float blds[16][32];
  int bid = blockIdx.x;
  int sb = bid & 15, c = (bid >> 4) & 7, b = bid >> 7;
  int t = threadIdx.x;  // = l
  int tok0 = b * 2048 + c * 256;
  float acc[16];
#pragma unroll
  for (int i = 0; i < 16; ++i) acc[i] = 0.f;
  for (int nh = 0; nh < 2; ++nh) {
    __syncthreads();
    for (int it = 0; it < 32; ++it) {
      int e = it * 256 + t;
      int row = e >> 5, n = e & 31;
      cl[row][n] = bf2f(zx[(size_t)(tok0 + row) * DPROJ + 8256 + nh * 32 + n]);
    }
    for (int it = 0; it < 2; ++it) {
      int e = it * 256 + t;
      int row = e >> 5, n = e & 31;
      blds[row][n] =
          bf2f(zx[(size_t)(tok0 + sb * 16 + row) * DPROJ + 8192 + nh * 32 + n]);
    }
    __syncthreads();
    for (int n = 0; n < 32; ++n) {
      float cv = cl[t][n];
#pragma unroll
      for (int s2 = 0; s2 < 16; ++s2) acc[s2] += cv * blds[s2][n];
    }
  }
  short* outp = cbtT + ((size_t)(b * 8 + c) * 256 + t) * 256 + sb * 16;
#pragma unroll
  for (int s2 = 0; s2 < 16; ++s2) outp[s2] = f2bf(acc[s2]);
}

// ---------------- states (MFMA): st[p][n] = sum_s x[s,p] B[s,n] w[s] ---------
__global__ __launch_bounds__(256) void states_mfma(
    const short* __restrict__ zx, const float* __restrict__ dtb,
    const float* __restrict__ acu, float* __restrict__ st) {
  __shared__ __align__(16) short As2[64][136];  // X^T [p][k]
  __shared__ __align__(16) short Bs2[64][136];  // (B·w)^T [n][k]
  __shared__ float wl[256];
  int bid = blockIdx.x;  // (b*8+c)*64 + h
  int h = bid & 63, c = (bid >> 6) & 7, b = bid >> 9;
  int t = threadIdx.x;
  int w = t >> 6, lane = t & 63;
  int tok0 = b * 2048 + c * 256;
  int bh = (b * 64 + h) * 2048 + c * 256;
  {
    float aend = acu[bh + 255];
    wl[t] = __expf(aend - acu[bh + t]) * dtb[bh + t];
  }
  __syncthreads();
  const short* xbase = zx + (size_t)tok0 * DPROJ + 4096 + h * 64;
  const short* bbase = zx + (size_t)tok0 * DPROJ + 8192;
  const int fr = lane & 15, fko = (lane >> 4) * 8;
  const int wi = (w >> 1) * 32, wj = (w & 1) * 32;
  f32x4 acc[2][2];
#pragma unroll
  for (int i = 0; i < 2; ++i)
#pragma unroll
    for (int j = 0; j < 2; ++j) acc[i][j] = (f32x4){0.f, 0.f, 0.f, 0.f};

  for (int ph = 0; ph < 2; ++ph) {
    const int kb = ph * 128;
    if (ph) __syncthreads();
    for (int it = 0; it < 8; ++it) {
      int idx = it * 256 + t;
      int p = idx & 63, kg = idx >> 6;  // kg 0..31
      int k = kb + kg * 4;
      const short* xp = xbase + (size_t)k * DPROJ + p;
      const short* bp = bbase + (size_t)k * DPROJ + p;
      sh4 oa, ob;
#pragma unroll
      for (int r = 0; r < 4; ++r) {
        oa[r] = xp[(size_t)r * DPROJ];
        ob[r] = f2bf(bf2f(bp[(size_t)r * DPROJ]) * wl[k + r]);
      }
      *(sh4*)&As2[p][kg * 4] = oa;
      *(sh4*)&Bs2[p][kg * 4] = ob;
    }
    __syncthreads();
#pragma unroll
    for (int kk0 = 0; kk0 < 128; kk0 += 32) {
      short8 af[2], bg[2];
#pragma unroll
      for (int i = 0; i < 2; ++i) {
        af[i] = *(const short8*)&As2[wi + i * 16 + fr][kk0 + fko];
        bg[i] = *(const short8*)&Bs2[wj + i * 16 + fr][kk0 + fko];
      }
#pragma unroll
      for (int i = 0; i < 2; ++i)
#pragma unroll
        for (int j = 0; j < 2; ++j)
          acc[i][j] = __builtin_amdgcn_mfma_f32_16x16x32_bf16(af[i], bg[j],
                                                              acc[i][j], 0, 0, 0);
    }
  }
  float* out = st + ((size_t)(b * 8 + c) * 64 + h) * 4096;
  const int rq = (lane >> 4) * 4;
#pragma unroll
  for (int i = 0; i < 2; ++i) {
    int p0 = wi + i * 16 + rq;
#pragma unroll
    for (int j = 0; j < 2; ++j) {
      int n = wj + j * 16 + fr;
#pragma unroll
      for (int r = 0; r < 4; ++r)
        out[(size_t)(p0 + r) * 64 + n] = acc[i][j][r];
    }
  }
}

// ---------------- inter-chunk scan (in place states -> prev_states) ---------
__global__ __launch_bounds__(256) void chunkscan_kernel(
    const float* __restrict__ acu, float* __restrict__ st) {
  int bid = blockIdx.x;
  int pc = bid & 15, h = (bid >> 4) & 63, b = bid >> 10;
  int pn = pc * 256 + threadIdx.x;
  int abase = (b * 64 + h) * 2048;
  float run = 0.f;
  for (int c = 0; c < 8; ++c) {
    size_t idx = ((size_t)(b * 8 + c) * 64 + h) * 4096 + pn;
    float s = st[idx];
    st[idx] = run;
    float ach = acu[abase + c * 256 + 255];
    run = run * __expf(ach) + s;
  }
}

// ---------------- Y (MFMA): M=256 l, N=64 p, K=320 (256 s + 64 n) ------------
__global__ __launch_bounds__(256) void ydiag_mfma(
    const short* __restrict__ zx, const float* __restrict__ dtb,
    const float* __restrict__ acu, const short* __restrict__ cbtT,
    const float* __restrict__ st, const float* __restrict__ Dp,
    short* __restrict__ yb) {
  __shared__ __align__(16) short Xs[64][328];  // [p][k]: k<256 x, k>=256 prev
  __shared__ float acs[256];
  __shared__ float dts[256];
  int bid = blockIdx.x;  // (b*8+c)*64 + h
  int h = bid & 63, c = (bid >> 6) & 7, b = bid >> 9;
  int t = threadIdx.x;
  int w = t >> 6, lane = t & 63;
  int tok0 = b * 2048 + c * 256;
  int bh = (b * 64 + h) * 2048 + c * 256;
  acs[t] = acu[bh + t];
  dts[t] = dtb[bh + t];
  const short* xbase = zx + (size_t)tok0 * DPROJ + 4096 + h * 64;
  const float* st_b = st + ((size_t)(b * 8 + c) * 64 + h) * 4096;
  for (int it = 0; it < 16; ++it) {
    int idx = it * 256 + t;
    int p = idx & 63, kg = idx >> 6;  // kg 0..63
    const short* xp = xbase + (size_t)(kg * 4) * DPROJ + p;
    sh4 o;
    o[0] = xp[0];
    o[1] = xp[DPROJ];
    o[2] = xp[2 * DPROJ];
    o[3] = xp[3 * DPROJ];
    *(sh4*)&Xs[p][kg * 4] = o;
  }
  for (int it = 0; it < 4; ++it) {
    int idx = it * 256 + t;
    int ng = idx & 15, p = idx >> 4;
    float4 v = *(const float4*)&st_b[p * 64 + ng * 4];
    sh4 o;
    o[0] = f2bf(v.x); o[1] = f2bf(v.y); o[2] = f2bf(v.z); o[3] = f2bf(v.w);
    *(sh4*)&Xs[p][256 + ng * 4] = o;
  }
  __syncthreads();

  const int fr = lane & 15, fko = (lane >> 4) * 8;
  float Al[4], eAl[4];
#pragma unroll
  for (int i = 0; i < 4; ++i) {
    Al[i] = acs[(i * 4 + w) * 16 + fr];
    eAl[i] = __expf(Al[i]);
  }
  f32x4 acc[4][4];
#pragma unroll
  for (int i = 0; i < 4; ++i)
#pragma unroll
    for (int j = 0; j < 4; ++j) acc[i][j] = (f32x4){0.f, 0.f, 0.f, 0.f};

  const short* cbt_b = cbtT + (size_t)(b * 8 + c) * 65536;

  // masked decay part: wave w's max row-block is 12+w
  const int k0max = (12 + w) * 16 + 16;
  for (int k0 = 0; k0 < k0max; k0 += 32) {
    short8 bg[4];
#pragma unroll
    for (int j = 0; j < 4; ++j)
      bg[j] = *(const short8*)&Xs[j * 16 + fr][k0 + fko];
    const int bi = (k0 + 32 < 256) ? (k0 + 32) : 255;
    const float base = acs[bi];
    float vd[8];
#pragma unroll
    for (int jj = 0; jj < 8; ++jj) {
      int s = k0 + fko + jj;
      vd[jj] = __expf(base - acs[s]) * dts[s];
    }
#pragma unroll
    for (int i = 0; i < 4; ++i) {
      const int li0 = (i * 4 + w) * 16;
      if (k0 > li0 + 15) continue;  // fragment fully above diagonal: zero
      const int l = li0 + fr;
      const short8 cb = *(const short8*)&cbt_b[(size_t)l * 256 + k0 + fko];
      short8 af;
      if (k0 + 32 <= li0) {
        const float u = __expf(Al[i] - base);
#pragma unroll
        for (int jj = 0; jj < 8; ++jj)
          af[jj] = f2bf(bf2f(cb[jj]) * (vd[jj] * u));
      } else {
#pragma unroll
        for (int jj = 0; jj < 8; ++jj) {
          int s = k0 + fko + jj;
          float wv = 0.f;
          if (s <= l) wv = bf2f(cb[jj]) * __expf(Al[i] - acs[s]) * dts[s];
          af[jj] = f2bf(wv);
        }
      }
#pragma unroll
      for (int j = 0; j < 4; ++j)
        acc[i][j] = __builtin_amdgcn_mfma_f32_16x16x32_bf16(af, bg[j],
                                                            acc[i][j], 0, 0, 0);
    }
  }
  // Y_off part: k in [256, 320) -> n = k-256; C read straight from zx (bf16)
#pragma unroll
  for (int k0 = 256; k0 < 320; k0 += 32) {
    short8 bg[4];
#pragma unroll
    for (int j = 0; j < 4; ++j)
      bg[j] = *(const short8*)&Xs[j * 16 + fr][k0 + fko];
#pragma unroll
    for (int i = 0; i < 4; ++i) {
      const int l = (i * 4 + w) * 16 + fr;
      const short8 cv = *(const short8*)(zx + (size_t)(tok0 + l) * DPROJ +
                                         8256 + (k0 - 256) + fko);
      short8 af;
#pragma unroll
      for (int jj = 0; jj < 8; ++jj) af[jj] = f2bf(bf2f(cv[jj]) * eAl[i]);
#pragma unroll
      for (int j = 0; j < 4; ++j)
        acc[i][j] = __builtin_amdgcn_mfma_f32_16x16x32_bf16(af, bg[j],
                                                            acc[i][j], 0, 0, 0);
    }
  }
  // epilogue: + D*x, store bf16
  float Dh = Dp[h];
  const int rq = (lane >> 4) * 4;
#pragma unroll
  for (int i = 0; i < 4; ++i) {
    int l0 = (i * 4 + w) * 16 + rq;
#pragma unroll
    for (int j = 0; j < 4; ++j) {
      int p = j * 16 + fr;
      sh4 x4 = *(const sh4*)&Xs[p][l0];
      f32x4 a = acc[i][j];
#pragma unroll
      for (int r = 0; r < 4; ++r)
        yb[(size_t)(bh + l0 + r) * 64 + p] = f2bf(a[r] + Dh * bf2f(x4[r]));
    }
  }
}

// -------- gate + RMSNorm -> bf16 in place, 16 contiguous ch per thread -------
__global__ __launch_bounds__(256) void gatenorm_kernel(
    short* zx, const float* __restrict__ nw, const short* __restrict__ yb) {
  int tok = blockIdx.x;
  int b = tok >> 11, l = tok & 2047;
  int t = threadIdx.x;
  const int d0 = t * 16;                    // 16 contiguous channels
  const int h = d0 >> 6, p0 = d0 & 63;      // one h, p0..p0+15
  short8 yv8[2], zv8[2];
  yv8[0] = *(const short8*)&yb[((size_t)(b * 64 + h) * 2048 + l) * 64 + p0];
  yv8[1] = *(const short8*)&yb[((size_t)(b * 64 + h) * 2048 + l) * 64 + p0 + 8];
  zv8[0] = *(const short8*)&zx[(size_t)tok * DPROJ + d0];
  zv8[1] = *(const short8*)&zx[(size_t)tok * DPROJ + d0 + 8];
  float g[16];
  float ss = 0.f;
#pragma unroll
  for (int i = 0; i < 16; ++i) {
    float yv = bf2f(yv8[i >> 3][i & 7]);
    float zv = bf2f(zv8[i >> 3][i & 7]);
    float gv = yv * (zv / (1.f + __expf(-zv)));
    g[i] = gv;
    ss += gv * gv;
  }
  for (int off = 32; off > 0; off >>= 1) ss += __shfl_down(ss, off);
  __shared__ float red[4];
  int wid = t >> 6, lane = t & 63;
  if (lane == 0) red[wid] = ss;
  __syncthreads();
  float tot = red[0] + red[1] + red[2] + red[3];
  float scale = rsqrtf(tot * (1.f / 4096.f) + 1e-5f);
  short8 o[2];
#pragma unroll
  for (int i = 0; i < 16; ++i)
    o[i >> 3][i & 7] = f2bf(g[i] * scale * nw[d0 + i]);
  *(short8*)&zx[(size_t)tok * DPROJ + d0] = o[0];
  *(short8*)&zx[(size_t)tok * DPROJ + d0 + 8] = o[1];
}

extern "C" void kernel_launch(void* const* d_in, const int* in_sizes, int n_in,
                              void* d_out, int out_size, void* d_ws,
                              size_t ws_size, hipStream_t stream) {
  const float* u = (const float*)d_in[0];
  const float* W_in = (const float*)d_in[1];
  const float* conv_w = (const float*)d_in[2];
  const float* conv_b = (const float*)d_in[3];
  const float* dt_bias = (const float*)d_in[4];
  const float* A_log = (const float*)d_in[5];
  const float* Dp = (const float*)d_in[6];
  const float* norm_w = (const float*)d_in[7];
  const float* W_out = (const float*)d_in[8];
  float* out = (float*)d_out;
  float* ws = (float*)d_ws;

  short* zx16 = (short*)(ws + ZX16_OFF);
  float* dtb = ws + DTB_OFF;
  float* acu = ws + ACU_OFF;
  short* cbtT = (short*)(ws + CBT_OFF);
  float* st = ws + ST_OFF;
  short* yb = (short*)(ws + YB_OFF);
  short* halo = (short*)(ws + HALO_OFF);
  short* u16 = (short*)(ws + U16_OFF);
  short* win16 = (short*)(ws + WIN16_OFF);
  short* wout16 = (short*)(ws + WOUT16_OFF);

  // 0. merged casts for in_proj (u: 1048576 x8, W_in: 2146304 x8)
  cast2_bf16_kernel<<<12480, 256, 0, stream>>>(u, u16, 1048576, W_in, win16,
                                               2146304);
  // 1. in_proj (bf16 out, 256x128 tile, BK=64): zx16 = u @ W_in^T
  gemm_big<1><<<dim3(66, 16), 512, 0, stream>>>(u16, 2048, win16, 2048, zx16,
                                                DPROJ, 2048, DPROJ);
  // 2. conv halo (bf16), in-place conv+silu (2 ch/thread)
  halo_kernel<<<1584, 256, 0, stream>>>(zx16, halo);
  conv_kernel<<<264, 256, 0, stream>>>(zx16, halo, conv_w, conv_b);
  // 3. dt softplus + per-chunk cumsum
  dtacum_kernel<<<1024, 256, 0, stream>>>(zx16, dt_bias, A_log, dtb, acu);
  // 4. shared C·B^T (transposed bf16)
  cbt_kernel<<<256, 256, 0, stream>>>(zx16, cbtT);
  // 5. chunk states (MFMA) + inter-chunk scan
  states_mfma<<<1024, 256, 0, stream>>>(zx16, dtb, acu, st);
  chunkscan_kernel<<<2048, 256, 0, stream>>>(acu, st);
  // 6. Y (MFMA, load-balanced) -> bf16 yb
  ydiag_mfma<<<1024, 256, 0, stream>>>(zx16, dtb, acu, cbtT, st, Dp, yb);
  // 7. W_out cast (u16 region dead now)
  cast_bf16_kernel<<<4096, 256, 0, stream>>>(W_out, wout16, 1048576);
  // 8. gate + RMSNorm -> bf16 in place over z-slice (short8)
  gatenorm_kernel<<<4096, 256, 0, stream>>>(zx16, norm_w, yb);
  // 9. out_proj (fp32 out, 128x128 tile, BK=64): out = norm(y) @ W_out^T
  gemm_bf16<0><<<dim3(16, 32), 256, 0, stream>>>(zx16, DPROJ, wout16, 4096, out,
                                                 2048, 4096, 2048);
}